// Round 3
// baseline (964.456 us; speedup 1.0000x reference)
//
#include <hip/hip_runtime.h>
#include <hip/hip_bf16.h>

typedef __attribute__((ext_vector_type(8))) short bf16x8;
typedef __attribute__((ext_vector_type(4))) float f32x4;
typedef unsigned int u32;
typedef const __attribute__((address_space(1))) u32 glb_u32;
typedef __attribute__((address_space(3))) u32 lds_u32;

#define NB 16
#define CI 512
#define CO 512
#define PC 66              // conv output spatial (64 + 2*2 - 3 + 1)
#define PADD 68            // padded input spatial
#define NCOLS (NB*PC*PC)   // 69696

// workspace layout (bytes)
#define WS_STYLES 0ul              // 8192 f32
#define WS_SNORM  32768ul          // 1 f32
#define WS_D      33024ul          // 8192 f32
#define WS_W2     65792ul          // 512*512 f32
#define WS_AT     1114368ul        // 144*512*32 bf16 = 4718592
#define WS_XS     5832960ul        // 16*68*68*512 bf16 = 75759616
#define WS_CONV   81592576ul       // 16*512*66*66 bf16 = 71368704

// ---------------- styles = w @ aw^T / sqrt(512) + bias ----------------
__global__ void k_styles(const float* __restrict__ w, const float* __restrict__ aw,
                         const float* __restrict__ ab, float* __restrict__ styles) {
  int idx = blockIdx.x * 256 + threadIdx.x;   // 8192 = 16*512
  int n = idx >> 9, i = idx & 511;
  const float4* wr4 = (const float4*)(w + n * 512);
  const float4* ar4 = (const float4*)(aw + i * 512);
  float s = 0.f;
  for (int j = 0; j < 128; ++j) {
    float4 a = wr4[j], b = ar4[j];
    s += a.x * b.x + a.y * b.y + a.z * b.z + a.w * b.w;
  }
  styles[idx] = s * 0.04419417382415922f + ab[i];
}

// ---------------- snorm = rsqrt(mean(styles^2)) ----------------
__global__ void k_snorm(const float* __restrict__ styles, float* __restrict__ snorm) {
  __shared__ float red[256];
  float s = 0.f;
  for (int e = threadIdx.x; e < 8192; e += 256) { float v = styles[e]; s += v * v; }
  red[threadIdx.x] = s;
  __syncthreads();
  for (int st = 128; st > 0; st >>= 1) {
    if (threadIdx.x < st) red[threadIdx.x] += red[threadIdx.x + st];
    __syncthreads();
  }
  if (threadIdx.x == 0) snorm[0] = rsqrtf(red[0] / 8192.f);
}

// ---------------- weight prep: normalize per-o, write tiled bf16 A + W2 ----------------
// kt = ic*9 + rs  (ic = i>>5, rs = ry*3+rx); At[kt][o][ik]
__global__ void k_wprep(const float* __restrict__ cw, __hip_bfloat16* __restrict__ At,
                        float* __restrict__ W2) {
  int o = blockIdx.x;
  const float* base = cw + o * 4608;
  __shared__ float red[256];
  __shared__ float wnorm_s;
  float s = 0.f;
  for (int e = threadIdx.x; e < 4608; e += 256) { float v = base[e]; s += v * v; }
  red[threadIdx.x] = s;
  __syncthreads();
  for (int st = 128; st > 0; st >>= 1) {
    if (threadIdx.x < st) red[threadIdx.x] += red[threadIdx.x + st];
    __syncthreads();
  }
  if (threadIdx.x == 0) wnorm_s = rsqrtf(red[0] / 4608.f);
  __syncthreads();
  float wn = wnorm_s;
  for (int i = threadIdx.x; i < 512; i += 256) {
    const float* e9 = cw + (o * 512 + i) * 9;
    float w2 = 0.f;
    int ic = i >> 5, ik = i & 31;
#pragma unroll
    for (int rs = 0; rs < 9; ++rs) {
      float wv = e9[rs] * wn;
      w2 += wv * wv;
      At[((ic * 9 + rs) * 512 + o) * 32 + ik] = __float2bfloat16(wv);
    }
    W2[o * 512 + i] = w2;
  }
}

// ---------------- d[n,o] = rsqrt(snorm^2 * sum_i W2[o,i]*styles[n,i]^2 + 1e-8) ----------------
__global__ void k_dcalc(const float* __restrict__ W2, const float* __restrict__ styles,
                        const float* __restrict__ snorm, float* __restrict__ d) {
  int idx = blockIdx.x * 256 + threadIdx.x;   // n*512 + o
  int n = idx >> 9, o = idx & 511;
  const float4* w2r = (const float4*)(W2 + o * 512);
  const float4* sr = (const float4*)(styles + n * 512);
  float sum = 0.f;
  for (int i = 0; i < 128; ++i) {
    float4 a = w2r[i], b = sr[i];
    sum += a.x * b.x * b.x + a.y * b.y * b.y + a.z * b.z * b.z + a.w * b.w * b.w;
  }
  float sn = snorm[0];
  d[idx] = rsqrtf(sn * sn * sum + 1e-8f);
}

// ---------------- zero only the pad border of xs ----------------
__global__ void k_zero_border(uint4* __restrict__ p) {
  int e = blockIdx.x * 256 + threadIdx.x;     // 16*528*64 = 540672
  if (e >= 16 * 528 * 64) return;
  int chunk = e & 63;
  int rest = e >> 6;
  int n = rest / 528;
  int pos = rest - n * 528;
  int row, col;
  if (pos < 272) {
    int r = pos / 68;
    row = (r < 2) ? r : r + 64;
    col = pos - r * 68;
  } else {
    int q = pos - 272;
    row = 2 + (q >> 2);
    int cs = q & 3;
    col = (cs < 2) ? cs : cs + 64;
  }
  uint4 z = {0u, 0u, 0u, 0u};
  p[(n * 4624 + row * 68 + col) * 64 + chunk] = z;
}

// ---------------- scale by s[n,i], transpose NCHW -> N,H+4,W+4,C (bf16) ----------------
__global__ void k_scale_tr(const float* __restrict__ x, const float* __restrict__ styles,
                           const float* __restrict__ snorm, __hip_bfloat16* __restrict__ xs) {
  const int i0 = blockIdx.x * 64;
  const int p = blockIdx.y;
  const int n = blockIdx.z;
  __shared__ float tile[64][65];
  const float sn = snorm[0];
  const int lo = threadIdx.x & 63;
  const int hi = threadIdx.x >> 6;
#pragma unroll 4
  for (int rep = 0; rep < 16; ++rep) {
    int ii = hi + rep * 4;
    float sc = styles[n * 512 + i0 + ii] * sn;
    tile[ii][lo] = x[((n * 512 + i0 + ii) * 64 + p) * 64 + lo] * sc;
  }
  __syncthreads();
  const int obase = (n * 4624 + (p + 2) * 68 + 2) * 512 + i0;
#pragma unroll 4
  for (int rep = 0; rep < 16; ++rep) {
    int q = hi + rep * 4;
    xs[obase + q * 512 + lo] = __float2bfloat16(tile[lo][q]);
  }
}

// ---------------- implicit GEMM conv: 256x128 tile, A global->reg, B-only LDS ----------------
__device__ __forceinline__ int colbase_of(int c) {
  c = c < (NCOLS - 1) ? c : (NCOLS - 1);
  int n = (int)((unsigned)c / 4356u);
  int rem = c - n * 4356;
  int p = (int)((unsigned)rem / 66u);
  int q = rem - p * 66;
  return (n * 4624 + p * 68 + q) * 512;
}

// B LDS: 4 rotating buffers x 8 KB. Buffer: 128 cols x 64 B (32 k bf16), packed
// 2 cols per 128-B lds-row -> 64 lds-rows. 16B slot s within lds-row p is
// XOR-swizzled: s_phys = s_log ^ (p&7). gload_lds dest is linear tid*16; swizzle
// realized by inverse-permuting the per-lane GLOBAL source.
// A: loaded global->registers directly (At is L2/L3-hot), one-step prefetch.

#define GLD(G, L) __builtin_amdgcn_global_load_lds((glb_u32*)(G), (lds_u32*)(L), 16, 0, 0)
#define BARR() __builtin_amdgcn_s_barrier()
#define VMC10() asm volatile("s_waitcnt vmcnt(10)" ::: "memory")
#define VMC8()  asm volatile("s_waitcnt vmcnt(8)" ::: "memory")
#define VMC2()  asm volatile("s_waitcnt vmcnt(2)" ::: "memory")

// stage B tile KT into buffer KT&3 (2 gload_lds per thread, 8 KB per block)
#define STAGEB(KT) do { \
    int _kt = (KT); \
    int _ic = (_kt * 456) >> 12; int _rs = _kt - 9 * _ic; \
    int _ry = (_rs * 11) >> 5; int _rx = _rs - 3 * _ry; \
    int _ko = _ry * 69632 + _rx * 1024 + _ic * 64; \
    char* _l = smem + (_kt & 3) * 8192 + tid * 16; \
    GLD(xsB0 + _ko, _l); \
    GLD(xsB1 + _ko, _l + 4096); } while (0)

// one BK=32 step: read B frags from buf[T&3], prefetch A frags for T+1 into NXT,
// stage B tile T+2, 32 MFMA on CUR. Caller appends the counted vmcnt + barrier.
#define STEP(T, CUR, NXT, DO_AF, DO_STAGE) do { \
    const char* _bb = smem + ((T) & 3) * 8192 + rdB; \
    bf16x8 _bf0 = *(const bf16x8*)(_bb); \
    bf16x8 _bf1 = *(const bf16x8*)(_bb + 1024); \
    bf16x8 _bf2 = *(const bf16x8*)(_bb + 2048); \
    bf16x8 _bf3 = *(const bf16x8*)(_bb + 3072); \
    if (DO_AF) { \
      const char* _ap = ApC + (size_t)((T) + 1) * 32768; \
      _Pragma("unroll") for (int _m = 0; _m < 8; ++_m) \
        NXT[_m] = *(const bf16x8*)(_ap + _m * 1024); \
    } \
    if (DO_STAGE) STAGEB((T) + 2); \
    __builtin_amdgcn_s_setprio(1); \
    _Pragma("unroll") for (int _m = 0; _m < 8; ++_m) { \
      acc[_m][0] = __builtin_amdgcn_mfma_f32_16x16x32_bf16(CUR[_m], _bf0, acc[_m][0], 0, 0, 0); \
      acc[_m][1] = __builtin_amdgcn_mfma_f32_16x16x32_bf16(CUR[_m], _bf1, acc[_m][1], 0, 0, 0); \
      acc[_m][2] = __builtin_amdgcn_mfma_f32_16x16x32_bf16(CUR[_m], _bf2, acc[_m][2], 0, 0, 0); \
      acc[_m][3] = __builtin_amdgcn_mfma_f32_16x16x32_bf16(CUR[_m], _bf3, acc[_m][3], 0, 0, 0); \
    } \
    __builtin_amdgcn_s_setprio(0); } while (0)

__global__ __launch_bounds__(256, 2) void k_gemm(
    const __hip_bfloat16* __restrict__ At, const __hip_bfloat16* __restrict__ xs,
    const float* __restrict__ dnorm, const float* __restrict__ cbias,
    __hip_bfloat16* __restrict__ cvt) {
  __shared__ __align__(16) char smem[32768];
  const int tid = threadIdx.x;

  // bijective XCD swizzle over nwg=1090 (q=136, r=2); (colt, ot) pairs adjacent so the
  // two o-tiles sharing a B panel land on the same XCD L2.
  const int bid = blockIdx.x;
  const int xcd = bid & 7, sidx = bid >> 3;
  const int wgid = (xcd < 2 ? xcd * 137 : 274 + (xcd - 2) * 136) + sidx;
  const int o0 = (wgid & 1) * 256;
  const int c0 = (wgid >> 1) * 128;

  const int lane = tid & 63, wave = tid >> 6;
  const int wr = wave >> 1, wc = wave & 1;          // 2M x 2N waves, 128x64 out each
  const int r16 = lane & 15, sx = lane >> 4;
  // B frag read: col c -> lds-row c>>1, slot ((c&1)*4+sx)^(row&7)
  const int poff = (r16 >> 1) * 128 + (((((r16 & 1) << 2) | sx)) ^ (r16 >> 1)) * 16;
  const int rdB = wc * 4096 + poff;                  // + n*1024 + buf*8192

  // B staging: dest lds-row = tid>>3 (call2: +32), phys slot = tid&7
  const int p8 = (tid >> 3) & 7;
  const int s_log = (tid & 7) ^ p8;
  const int r0 = 2 * (tid >> 3) + (s_log >> 2);      // source col within 64-col group
  const int kc = s_log & 3;                          // 16B chunk within 64B k-cell
  const char* xsC = (const char*)xs;
  const char* xsB0 = xsC + (size_t)(colbase_of(c0 + r0) * 2 + kc * 16);
  const char* xsB1 = xsC + (size_t)(colbase_of(c0 + 64 + r0) * 2 + kc * 16);

  // A direct-load base: row o0 + wr*128 + r16, k-chunk sx*8 elems; af[m] at +m*1024 B
  const char* ApC = (const char*)(At + (size_t)(o0 + wr * 128 + r16) * 32 + sx * 8);

  f32x4 acc[8][4];
#pragma unroll
  for (int i = 0; i < 8; ++i)
#pragma unroll
    for (int j = 0; j < 4; ++j) acc[i][j] = (f32x4){0.f, 0.f, 0.f, 0.f};
  bf16x8 afA[8], afB[8];

  // prologue: af(0) -> afA; stage B tiles 0,1; force af(0)+stage(0), leave stage(1)
#pragma unroll
  for (int m = 0; m < 8; ++m)
    afA[m] = *(const bf16x8*)(ApC + m * 1024);
  STAGEB(0);
  STAGEB(1);
  VMC2(); BARR();

  for (int kp = 0; kp < 71; ++kp) {
    const int t0 = 2 * kp;
    STEP(t0, afA, afB, 1, 1);
    VMC10(); BARR();                 // stage(t0+1) landed; af(t0+1)+stage(t0+2) in flight
    STEP(t0 + 1, afB, afA, 1, 1);
    VMC10(); BARR();
  }
  STEP(142, afA, afB, 1, 0);
  VMC8(); BARR();                    // stage(143) landed; af(143) in flight
  STEP(143, afB, afA, 0, 0);

  // epilogue: *d[n,o] + bias[o], store bf16 NCHW [16][512][66][66]
  const int cb2 = c0 + wc * 64 + r16;
  const int rb = o0 + wr * 128 + (sx << 2);
#pragma unroll
  for (int nt = 0; nt < 4; ++nt) {
    int c = cb2 + nt * 16;
    if (c < NCOLS) {
      int n = (int)((unsigned)c / 4356u);
      int cadr = c + n * 2225916;   // == n*512*4356 + p*66 + q
#pragma unroll
      for (int mt = 0; mt < 8; ++mt) {
#pragma unroll
        for (int reg = 0; reg < 4; ++reg) {
          int o = rb + mt * 16 + reg;
          float v = acc[mt][nt][reg] * dnorm[n * 512 + o] + cbias[o];
          cvt[cadr + o * 4356] = __float2bfloat16(v);
        }
      }
    }
  }
}

// ---------------- fused filtered_lrelu: full channel per block, sliding-window FIRs ----------------
#define CSW 76
#define VSW 77
#define DHW 67
__global__ __launch_bounds__(512) void k_flrelu(
    const __hip_bfloat16* __restrict__ cvt, const float* __restrict__ fup,
    const float* __restrict__ fdn, float* __restrict__ out) {
  const int ch = blockIdx.x;
  const int n = blockIdx.y;
  const int tid = threadIdx.x;

  __shared__ float u_s[9246];        // cs [75][76] then dh [138][67]
  __shared__ float vs_s[138 * VSW];  // vertical-up fine rows x coarse cols

  const float fu0 = fup[0], fu1 = fup[1], fu2 = fup[2], fu3 = fup[3];
  const float fu4 = fup[4], fu5 = fup[5], fu6 = fup[6], fu7 = fup[7];
  const float fu8 = fup[8], fu9 = fup[9], fu10 = fup[10], fu11 = fup[11];
  const float fd0 = fdn[0], fd1 = fdn[1], fd2 = fdn[2], fd3 = fdn[3];
  const float fd4 = fdn[4], fd5 = fdn[5], fd6 = fdn[6], fd7 = fdn[7];
  const float fd8 = fdn[8], fd9 = fdn[9], fd10 = fdn[10], fd11 = fdn[11];

  const __hip_bfloat16* src = cvt + (size_t)(n * 512 + ch) * 4356;

  // stage A: load coarse 75x75 halo (zero outside [0,66)^2)
  for (int e = tid; e < 75 * 75; e += 512) {
    int il = (int)((unsigned)e / 75u);
    int jl = e - il * 75;
    int i = il - 4, j = jl - 4;
    float v = 0.f;
    if (i >= 0 && i < 66 && j >= 0 && j < 66) v = __bfloat162float(src[i * 66 + j]);
    u_s[il * CSW + jl] = v;
  }
  __syncthreads();

  // stage B: vertical up-FIR, fully parallel over (pair m, col jl)
  for (int e = tid; e < 69 * 75; e += 512) {
    int m = (int)((unsigned)e / 75u);   // 0..68
    int jl = e - m * 75;
    const float* col = u_s + jl;
    float c0 = col[(m + 0) * CSW], c1 = col[(m + 1) * CSW], c2 = col[(m + 2) * CSW];
    float c3 = col[(m + 3) * CSW], c4 = col[(m + 4) * CSW], c5 = col[(m + 5) * CSW];
    float ve = fu1 * c0 + fu3 * c1 + fu5 * c2 + fu7 * c3 + fu9 * c4 + fu11 * c5;
    float vo = fu0 * c0 + fu2 * c1 + fu4 * c2 + fu6 * c3 + fu8 * c4 + fu10 * c5;
    vs_s[(2 * m) * VSW + jl] = ve;
    vs_s[(2 * m + 1) * VSW + jl] = vo;
  }
  __syncthreads();

  // stage C: fused h-up + lrelu + h-down per fine row, transposed-FIR accumulators
  if (tid < 276) {
    int h = (tid >= 138) ? 1 : 0;
    int fy = tid - h * 138;
    const float* vrow = vs_s + fy * VSW + 32 * h;
    float* dhrow = u_s + fy * DHW + 32 * h;
    float a0 = 0.f, a1 = 0.f, a2 = 0.f, a3 = 0.f, a4 = 0.f, a5 = 0.f;
    float w0 = vrow[0], w1 = vrow[1], w2 = vrow[2], w3 = vrow[3], w4 = vrow[4];
#pragma unroll
    for (int ql = 0; ql < 37; ++ql) {
      float w5 = vrow[ql + 5];
      float ge = fu1 * w0 + fu3 * w1 + fu5 * w2 + fu7 * w3 + fu9 * w4 + fu11 * w5;
      float go = fu0 * w0 + fu2 * w1 + fu4 * w2 + fu6 * w3 + fu8 * w4 + fu10 * w5;
      ge *= (ge >= 0.f) ? 5.656854249492381f : 1.1313708498984762f;
      go *= (go >= 0.f) ? 5.656854249492381f : 1.1313708498984762f;
      ge = fminf(fmaxf(ge, -256.f), 256.f);
      go = fminf(fmaxf(go, -256.f), 256.f);
      a0 += fd10 * ge + fd11 * go;
      a1 += fd8 * ge + fd9 * go;
      a2 += fd6 * ge + fd7 * go;
      a3 += fd4 * ge + fd5 * go;
      a4 += fd2 * ge + fd3 * go;
      a5 += fd0 * ge + fd1 * go;
      if (ql >= 5) dhrow[ql - 5] = a0;
      a0 = a1; a1 = a2; a2 = a3; a3 = a4; a4 = a5; a5 = 0.f;
      w0 = w1; w1 = w2; w2 = w3; w3 = w4; w4 = w5;
    }
  }
  __syncthreads();

  // stage E: vertical down, 8 bands x 8 rows, 12-register sliding window
  {
    int ox = tid & 63;
    int r = tid >> 6;                // band: oy in [8r, 8r+8)
    const float* dcol = u_s + ox;
    int f0 = 16 * r;
    float wreg[12];
#pragma unroll
    for (int k = 0; k < 10; ++k) wreg[k] = dcol[(f0 + k) * DHW];
    float* dst = out + (((size_t)(n * 512 + ch) * 64 + 8 * r) * 64) + ox;
#pragma unroll
    for (int oyl = 0; oyl < 8; ++oyl) {
      wreg[10] = dcol[(f0 + 2 * oyl + 10) * DHW];
      wreg[11] = dcol[(f0 + 2 * oyl + 11) * DHW];
      float s = fd0 * wreg[0] + fd1 * wreg[1] + fd2 * wreg[2] + fd3 * wreg[3] +
                fd4 * wreg[4] + fd5 * wreg[5] + fd6 * wreg[6] + fd7 * wreg[7] +
                fd8 * wreg[8] + fd9 * wreg[9] + fd10 * wreg[10] + fd11 * wreg[11];
      dst[oyl * 64] = s;
#pragma unroll
      for (int k = 0; k < 10; ++k) wreg[k] = wreg[k + 2];
    }
  }
}

extern "C" void kernel_launch(void* const* d_in, const int* in_sizes, int n_in,
                              void* d_out, int out_size, void* d_ws, size_t ws_size,
                              hipStream_t stream) {
  const float* x = (const float*)d_in[0];
  const float* w = (const float*)d_in[1];
  const float* aw = (const float*)d_in[2];
  const float* ab = (const float*)d_in[3];
  const float* cw = (const float*)d_in[4];
  const float* cb = (const float*)d_in[5];
  const float* fu = (const float*)d_in[6];
  const float* fd = (const float*)d_in[7];
  char* ws = (char*)d_ws;
  float* styles = (float*)(ws + WS_STYLES);
  float* snorm = (float*)(ws + WS_SNORM);
  float* dmat = (float*)(ws + WS_D);
  float* W2 = (float*)(ws + WS_W2);
  __hip_bfloat16* At = (__hip_bfloat16*)(ws + WS_AT);
  __hip_bfloat16* xs = (__hip_bfloat16*)(ws + WS_XS);
  __hip_bfloat16* cvt = (__hip_bfloat16*)(ws + WS_CONV);
  float* out = (float*)d_out;

  k_styles<<<32, 256, 0, stream>>>(w, aw, ab, styles);
  k_snorm<<<1, 256, 0, stream>>>(styles, snorm);
  k_wprep<<<512, 256, 0, stream>>>(cw, At, W2);
  k_dcalc<<<32, 256, 0, stream>>>(W2, styles, snorm, dmat);
  k_zero_border<<<(16 * 528 * 64 + 255) / 256, 256, 0, stream>>>((uint4*)xs);
  k_scale_tr<<<dim3(8, 64, 16), 256, 0, stream>>>(x, styles, snorm, xs);
  k_gemm<<<1090, 256, 0, stream>>>(At, xs, dmat, cb, cvt);
  k_flrelu<<<dim3(512, 16), 512, 0, stream>>>(cvt, fu, fd, out);
}

// Round 5
// 828.642 us; speedup vs baseline: 1.1639x; 1.1639x over previous
//
#include <hip/hip_runtime.h>
#include <hip/hip_bf16.h>

typedef __attribute__((ext_vector_type(8))) short bf16x8;
typedef __attribute__((ext_vector_type(8))) unsigned short u16x8;
typedef __attribute__((ext_vector_type(4))) float f32x4;
typedef unsigned int u32;
typedef const __attribute__((address_space(1))) u32 glb_u32;
typedef __attribute__((address_space(3))) u32 lds_u32;

#define NB 16
#define CI 512
#define CO 512
#define PC 66              // conv output spatial (64 + 2*2 - 3 + 1)
#define PADD 68            // padded input spatial
#define NCOLS (NB*PC*PC)   // 69696

// workspace layout (bytes)
#define WS_STYLES 0ul              // 8192 f32
#define WS_SNORM  32768ul          // 1 f32
#define WS_D      33024ul          // 8192 f32
#define WS_W2     65792ul          // 512*512 f32
#define WS_AT     1114368ul        // 144*512*32 bf16 = 4718592
#define WS_XS     5832960ul        // 16*68*68*512 bf16 = 75759616
#define WS_CONV   81592576ul       // 16*512*66*66 bf16 = 71368704

// ---------------- styles = w @ aw^T / sqrt(512) + bias ----------------
__global__ void k_styles(const float* __restrict__ w, const float* __restrict__ aw,
                         const float* __restrict__ ab, float* __restrict__ styles) {
  int idx = blockIdx.x * 256 + threadIdx.x;   // 8192 = 16*512
  int n = idx >> 9, i = idx & 511;
  const float4* wr4 = (const float4*)(w + n * 512);
  const float4* ar4 = (const float4*)(aw + i * 512);
  float s = 0.f;
  for (int j = 0; j < 128; ++j) {
    float4 a = wr4[j], b = ar4[j];
    s += a.x * b.x + a.y * b.y + a.z * b.z + a.w * b.w;
  }
  styles[idx] = s * 0.04419417382415922f + ab[i];
}

// ---------------- snorm = rsqrt(mean(styles^2)) ----------------
__global__ void k_snorm(const float* __restrict__ styles, float* __restrict__ snorm) {
  __shared__ float red[256];
  float s = 0.f;
  for (int e = threadIdx.x; e < 8192; e += 256) { float v = styles[e]; s += v * v; }
  red[threadIdx.x] = s;
  __syncthreads();
  for (int st = 128; st > 0; st >>= 1) {
    if (threadIdx.x < st) red[threadIdx.x] += red[threadIdx.x + st];
    __syncthreads();
  }
  if (threadIdx.x == 0) snorm[0] = rsqrtf(red[0] / 8192.f);
}

// ---------------- weight prep: normalize per-o, write tiled bf16 A + W2 ----------------
// kt = ic*9 + rs  (ic = i>>5, rs = ry*3+rx); At[kt][o][ik]
__global__ void k_wprep(const float* __restrict__ cw, __hip_bfloat16* __restrict__ At,
                        float* __restrict__ W2) {
  int o = blockIdx.x;
  const float* base = cw + o * 4608;
  __shared__ float red[256];
  __shared__ float wnorm_s;
  float s = 0.f;
  for (int e = threadIdx.x; e < 4608; e += 256) { float v = base[e]; s += v * v; }
  red[threadIdx.x] = s;
  __syncthreads();
  for (int st = 128; st > 0; st >>= 1) {
    if (threadIdx.x < st) red[threadIdx.x] += red[threadIdx.x + st];
    __syncthreads();
  }
  if (threadIdx.x == 0) wnorm_s = rsqrtf(red[0] / 4608.f);
  __syncthreads();
  float wn = wnorm_s;
  for (int i = threadIdx.x; i < 512; i += 256) {
    const float* e9 = cw + (o * 512 + i) * 9;
    float w2 = 0.f;
    int ic = i >> 5, ik = i & 31;
#pragma unroll
    for (int rs = 0; rs < 9; ++rs) {
      float wv = e9[rs] * wn;
      w2 += wv * wv;
      At[((ic * 9 + rs) * 512 + o) * 32 + ik] = __float2bfloat16(wv);
    }
    W2[o * 512 + i] = w2;
  }
}

// ---------------- d[n,o] = rsqrt(snorm^2 * sum_i W2[o,i]*styles[n,i]^2 + 1e-8) ----------------
__global__ void k_dcalc(const float* __restrict__ W2, const float* __restrict__ styles,
                        const float* __restrict__ snorm, float* __restrict__ d) {
  int idx = blockIdx.x * 256 + threadIdx.x;   // n*512 + o
  int n = idx >> 9, o = idx & 511;
  const float4* w2r = (const float4*)(W2 + o * 512);
  const float4* sr = (const float4*)(styles + n * 512);
  float sum = 0.f;
  for (int i = 0; i < 128; ++i) {
    float4 a = w2r[i], b = sr[i];
    sum += a.x * b.x * b.x + a.y * b.y * b.y + a.z * b.z * b.z + a.w * b.w * b.w;
  }
  float sn = snorm[0];
  d[idx] = rsqrtf(sn * sn * sum + 1e-8f);
}

// ---------------- zero only the pad border of xs ----------------
__global__ void k_zero_border(uint4* __restrict__ p) {
  int e = blockIdx.x * 256 + threadIdx.x;     // 16*528*64 = 540672
  if (e >= 16 * 528 * 64) return;
  int chunk = e & 63;
  int rest = e >> 6;
  int n = rest / 528;
  int pos = rest - n * 528;
  int row, col;
  if (pos < 272) {
    int r = pos / 68;
    row = (r < 2) ? r : r + 64;
    col = pos - r * 68;
  } else {
    int q = pos - 272;
    row = 2 + (q >> 2);
    int cs = q & 3;
    col = (cs < 2) ? cs : cs + 64;
  }
  uint4 z = {0u, 0u, 0u, 0u};
  p[(n * 4624 + row * 68 + col) * 64 + chunk] = z;
}

// ---------------- scale by s[n,i], transpose NCHW -> N,H+4,W+4,C (bf16) ----------------
// vectorized: float4 global loads, 16B (8-channel) bf16 stores
__global__ void k_scale_tr(const float* __restrict__ x, const float* __restrict__ styles,
                           const float* __restrict__ snorm, __hip_bfloat16* __restrict__ xs) {
  const int i0 = blockIdx.x * 64;
  const int p = blockIdx.y;
  const int n = blockIdx.z;
  __shared__ float tile[64][65];
  const float sn = snorm[0];
  const int tid = threadIdx.x;

  // stage 1: ch = tid>>4 (+16/rep), wq = (tid&15)*4; float4 load, scale, LDS
  {
    const int wq = (tid & 15) << 2;
#pragma unroll
    for (int rep = 0; rep < 4; ++rep) {
      int ch = (tid >> 4) + rep * 16;
      float sc = styles[n * 512 + i0 + ch] * sn;
      const float4 v = *(const float4*)(x + (((size_t)(n * 512 + i0 + ch) * 64 + p) * 64 + wq));
      tile[ch][wq + 0] = v.x * sc;
      tile[ch][wq + 1] = v.y * sc;
      tile[ch][wq + 2] = v.z * sc;
      tile[ch][wq + 3] = v.w * sc;
    }
  }
  __syncthreads();

  // stage 2: c8 = 8*(tid&7), q = (tid>>3) (+32/rep); pack 8 ch -> 16B store
  {
    const int c8 = (tid & 7) << 3;
    const size_t obase = ((size_t)n * 4624 + (size_t)(p + 2) * 68 + 2) * 512 + i0;
#pragma unroll
    for (int rep = 0; rep < 2; ++rep) {
      int q = (tid >> 3) + rep * 32;
      u16x8 pk;
#pragma unroll
      for (int j = 0; j < 8; ++j) {
        __hip_bfloat16 b = __float2bfloat16(tile[c8 + j][q]);
        pk[j] = *(unsigned short*)&b;
      }
      *(u16x8*)(xs + obase + (size_t)q * 512 + c8) = pk;
    }
  }
}

// ---------------- implicit GEMM conv: 256x128 tile, 256 threads, BK=32, 2 blocks/CU ----------------
__device__ __forceinline__ int colbase_of(int c) {
  c = c < (NCOLS - 1) ? c : (NCOLS - 1);
  int n = (int)((unsigned)c / 4356u);
  int rem = c - n * 4356;
  int p = (int)((unsigned)rem / 66u);
  int q = rem - p * 66;
  return (n * 4624 + p * 68 + q) * 512;
}

// LDS (static, 48 KiB): buf b at b*24576:
//   A: 256 rows x 32k bf16, packed 2 rows per 128B lds-row -> 128 lds-rows (16 KiB) @ +0
//   B: 128 cols x 32k bf16, same packing -> 64 lds-rows (8 KiB)  @ +16384
// 16B slot s within an lds-row p is XOR-swizzled: s_phys = s_log ^ (p&7) (involution).
// gload_lds dest is linear tid*16; swizzle realized by inverse-permuting the
// per-lane GLOBAL source (linear dest + inv-swz source + swz read).

#define GLD(G, L) __builtin_amdgcn_global_load_lds((glb_u32*)(G), (lds_u32*)(L), 16, 0, 0)
#define STAGE(KT2, KOFF2, CUR) do { \
    const char* _ga = AgA + (size_t)(KT2) * 32768; \
    char* _l = smem + (CUR) + sdst; \
    GLD(_ga, _l); \
    GLD(_ga + 4096, _l + 4096); \
    GLD(_ga + 8192, _l + 8192); \
    GLD(_ga + 12288, _l + 12288); \
    GLD(xsB0 + (KOFF2), _l + 16384); \
    GLD(xsB1 + (KOFF2), _l + 20480); } while (0)
#define BARR() __builtin_amdgcn_s_barrier()
#define LGKM() asm volatile("s_waitcnt lgkmcnt(0)" ::: "memory")
#define VMC6() asm volatile("s_waitcnt vmcnt(6)" ::: "memory")
#define VMC0() asm volatile("s_waitcnt vmcnt(0)" ::: "memory")

__global__ __launch_bounds__(256, 2) void k_gemm(
    const __hip_bfloat16* __restrict__ At, const __hip_bfloat16* __restrict__ xs,
    const float* __restrict__ dnorm, const float* __restrict__ cbias,
    __hip_bfloat16* __restrict__ cvt) {
  __shared__ __align__(16) char smem[49152];
  const int tid = threadIdx.x;

  // bijective XCD swizzle over nwg=1090 (q=136, r=2); (colt, ot) pairs adjacent so the
  // two o-tiles sharing a B panel land on the same XCD L2.
  const int bid = blockIdx.x;
  const int xcd = bid & 7, sidx = bid >> 3;
  const int wgid = (xcd < 2 ? xcd * 137 : 274 + (xcd - 2) * 136) + sidx;
  const int o0 = (wgid & 1) * 256;
  const int c0 = (wgid >> 1) * 128;

  const int lane = tid & 63, wave = tid >> 6;
  const int wr = wave >> 1, wc = wave & 1;          // 2M x 2N waves, 128x64 out each
  const int r16 = lane & 15, sx = lane >> 4;
  // fragment read offset inside a region: row R -> lds-row R>>1, slot ((R&1)*4+sx)^(R>>1 &7)
  const int poff = (r16 >> 1) * 128 + (((((r16 & 1) << 2) | sx)) ^ (r16 >> 1)) * 16;
  const int rdA = wr * 8192 + poff;                  // + m*1024 + curL
  const int rdB = 16384 + wc * 4096 + poff;          // + n*1024 + curL

  // staging constants: dest lds-row = h*32 + (tid>>3), phys slot = tid&7
  const int p8 = (tid >> 3) & 7;
  const int s_log = (tid & 7) ^ p8;
  const int r0 = 2 * (tid >> 3) + (s_log >> 2);      // source row within 64-row group
  const int kc = s_log & 3;                          // 16B chunk within 64B k-cell
  const int sdst = tid * 16;
  const char* AgA = (const char*)At + (size_t)(o0 + r0) * 64 + kc * 16;
  const char* xsC = (const char*)xs;
  const char* xsB0 = xsC + (size_t)(colbase_of(c0 + r0) * 2 + kc * 16);
  const char* xsB1 = xsC + (size_t)(colbase_of(c0 + 64 + r0) * 2 + kc * 16);

  f32x4 acc[8][4];
#pragma unroll
  for (int i = 0; i < 8; ++i)
#pragma unroll
    for (int j = 0; j < 4; ++j) acc[i][j] = (f32x4){0.f, 0.f, 0.f, 0.f};

  // prologue: stage tiles 0 and 1 (6 loads each); wait oldest 6 (tile 0)
  STAGE(0, 0, 0);
  STAGE(1, 1024, 24576);
  VMC6(); BARR();

  // kt -> B byte offset within a column: ry*69632 + rx*1024 + ic*64 (kt = ic*9 + ry*3 + rx)
  // OFF2[rs] = offset for rs2=(rs+2)%9 (compile-time under unroll)
  static const int OFF2[9] = {2048, 69632, 70656, 71680, 139264, 140288, 141312, 0, 1024};

  for (int ic = 0; ic < 16; ++ic) {
#pragma unroll
    for (int rs = 0; rs < 9; ++rs) {
      const int kt = ic * 9 + rs;
      const int curL = ((ic + rs) & 1) * 24576;
      bf16x8 af[8], bf[4];
#pragma unroll
      for (int m = 0; m < 8; ++m)
        af[m] = *(const bf16x8*)(smem + curL + rdA + m * 1024);
#pragma unroll
      for (int n = 0; n < 4; ++n)
        bf[n] = *(const bf16x8*)(smem + curL + rdB + n * 1024);
      LGKM();
      BARR();                                   // all waves done reading buf -> reusable
      if (kt < 142) {                           // stage tile kt+2 into the buffer just freed
        const int koff2 = OFF2[rs] + (ic + (rs + 2) / 9) * 64;
        STAGE(kt + 2, koff2, curL);
      }
      __builtin_amdgcn_s_setprio(1);
#pragma unroll
      for (int m = 0; m < 8; ++m)
#pragma unroll
        for (int n = 0; n < 4; ++n)
          acc[m][n] = __builtin_amdgcn_mfma_f32_16x16x32_bf16(af[m], bf[n], acc[m][n], 0, 0, 0);
      __builtin_amdgcn_s_setprio(0);
      if (kt < 143) {
        if (kt < 142) VMC6(); else VMC0();      // tile kt+1 landed (counted, no drain)
        BARR();
      }
    }
  }

  // epilogue: *d[n,o] + bias[o], store bf16 NCHW [16][512][66][66]
  const int cb2 = c0 + wc * 64 + r16;
  const int rb = o0 + wr * 128 + (sx << 2);
#pragma unroll
  for (int nt = 0; nt < 4; ++nt) {
    int c = cb2 + nt * 16;
    if (c < NCOLS) {
      int n = (int)((unsigned)c / 4356u);
      int cadr = c + n * 2225916;   // == n*512*4356 + p*66 + q
#pragma unroll
      for (int mt = 0; mt < 8; ++mt) {
#pragma unroll
        for (int reg = 0; reg < 4; ++reg) {
          int o = rb + mt * 16 + reg;
          float v = acc[mt][nt][reg] * dnorm[n * 512 + o] + cbias[o];
          cvt[cadr + o * 4356] = __float2bfloat16(v);
        }
      }
    }
  }
}

// ---------------- fused filtered_lrelu: full channel per block, sliding-window FIRs ----------------
#define CSW 76
#define VSW 77
#define DHW 67
__global__ __launch_bounds__(512) void k_flrelu(
    const __hip_bfloat16* __restrict__ cvt, const float* __restrict__ fup,
    const float* __restrict__ fdn, float* __restrict__ out) {
  const int ch = blockIdx.x;
  const int n = blockIdx.y;
  const int tid = threadIdx.x;

  __shared__ float u_s[9246];        // cs [75][76] then dh [138][67]
  __shared__ float vs_s[138 * VSW];  // vertical-up fine rows x coarse cols (stage A: raw bf16)

  const float fu0 = fup[0], fu1 = fup[1], fu2 = fup[2], fu3 = fup[3];
  const float fu4 = fup[4], fu5 = fup[5], fu6 = fup[6], fu7 = fup[7];
  const float fu8 = fup[8], fu9 = fup[9], fu10 = fup[10], fu11 = fup[11];
  const float fd0 = fdn[0], fd1 = fdn[1], fd2 = fdn[2], fd3 = fdn[3];
  const float fd4 = fdn[4], fd5 = fdn[5], fd6 = fdn[6], fd7 = fdn[7];
  const float fd8 = fdn[8], fd9 = fdn[9], fd10 = fdn[10], fd11 = fdn[11];

  const __hip_bfloat16* src = cvt + (size_t)(n * 512 + ch) * 4356;

  // stage A1: coalesced 8B raw copy of the 66x66 bf16 channel into vs_s scratch
  // (4356 bf16 = 8712 B = 1089 uint2; channel base is 8B-aligned since 8712%8==0)
  unsigned short* raw = (unsigned short*)vs_s;
  {
    const uint2* s2 = (const uint2*)src;
    uint2* d2 = (uint2*)raw;
    for (int e = tid; e < 1089; e += 512) d2[e] = s2[e];
  }
  __syncthreads();

  // stage A2: build coarse 75x75 f32 halo from LDS raw (zero outside [0,66)^2)
  for (int e = tid; e < 75 * 75; e += 512) {
    int il = (int)((unsigned)e / 75u);
    int jl = e - il * 75;
    int i = il - 4, j = jl - 4;
    float v = 0.f;
    if (i >= 0 && i < 66 && j >= 0 && j < 66)
      v = __bfloat162float(*(const __hip_bfloat16*)&raw[i * 66 + j]);
    u_s[il * CSW + jl] = v;
  }
  __syncthreads();   // raw fully consumed; stage B may overwrite vs_s

  // stage B: vertical up-FIR, fully parallel over (pair m, col jl)
  for (int e = tid; e < 69 * 75; e += 512) {
    int m = (int)((unsigned)e / 75u);   // 0..68
    int jl = e - m * 75;
    const float* col = u_s + jl;
    float c0 = col[(m + 0) * CSW], c1 = col[(m + 1) * CSW], c2 = col[(m + 2) * CSW];
    float c3 = col[(m + 3) * CSW], c4 = col[(m + 4) * CSW], c5 = col[(m + 5) * CSW];
    float ve = fu1 * c0 + fu3 * c1 + fu5 * c2 + fu7 * c3 + fu9 * c4 + fu11 * c5;
    float vo = fu0 * c0 + fu2 * c1 + fu4 * c2 + fu6 * c3 + fu8 * c4 + fu10 * c5;
    vs_s[(2 * m) * VSW + jl] = ve;
    vs_s[(2 * m + 1) * VSW + jl] = vo;
  }
  __syncthreads();

  // stage C: fused h-up + lrelu + h-down per fine row, transposed-FIR accumulators
  if (tid < 276) {
    int h = (tid >= 138) ? 1 : 0;
    int fy = tid - h * 138;
    const float* vrow = vs_s + fy * VSW + 32 * h;
    float* dhrow = u_s + fy * DHW + 32 * h;
    float a0 = 0.f, a1 = 0.f, a2 = 0.f, a3 = 0.f, a4 = 0.f, a5 = 0.f;
    float w0 = vrow[0], w1 = vrow[1], w2 = vrow[2], w3 = vrow[3], w4 = vrow[4];
#pragma unroll
    for (int ql = 0; ql < 37; ++ql) {
      float w5 = vrow[ql + 5];
      float ge = fu1 * w0 + fu3 * w1 + fu5 * w2 + fu7 * w3 + fu9 * w4 + fu11 * w5;
      float go = fu0 * w0 + fu2 * w1 + fu4 * w2 + fu6 * w3 + fu8 * w4 + fu10 * w5;
      ge *= (ge >= 0.f) ? 5.656854249492381f : 1.1313708498984762f;
      go *= (go >= 0.f) ? 5.656854249492381f : 1.1313708498984762f;
      ge = fminf(fmaxf(ge, -256.f), 256.f);
      go = fminf(fmaxf(go, -256.f), 256.f);
      a0 += fd10 * ge + fd11 * go;
      a1 += fd8 * ge + fd9 * go;
      a2 += fd6 * ge + fd7 * go;
      a3 += fd4 * ge + fd5 * go;
      a4 += fd2 * ge + fd3 * go;
      a5 += fd0 * ge + fd1 * go;
      if (ql >= 5) dhrow[ql - 5] = a0;
      a0 = a1; a1 = a2; a2 = a3; a3 = a4; a4 = a5; a5 = 0.f;
      w0 = w1; w1 = w2; w2 = w3; w3 = w4; w4 = w5;
    }
  }
  __syncthreads();

  // stage E: vertical down, 8 bands x 8 rows, 12-register sliding window
  {
    int ox = tid & 63;
    int r = tid >> 6;                // band: oy in [8r, 8r+8)
    const float* dcol = u_s + ox;
    int f0 = 16 * r;
    float wreg[12];
#pragma unroll
    for (int k = 0; k < 10; ++k) wreg[k] = dcol[(f0 + k) * DHW];
    float* dst = out + (((size_t)(n * 512 + ch) * 64 + 8 * r) * 64) + ox;
#pragma unroll
    for (int oyl = 0; oyl < 8; ++oyl) {
      wreg[10] = dcol[(f0 + 2 * oyl + 10) * DHW];
      wreg[11] = dcol[(f0 + 2 * oyl + 11) * DHW];
      float s = fd0 * wreg[0] + fd1 * wreg[1] + fd2 * wreg[2] + fd3 * wreg[3] +
                fd4 * wreg[4] + fd5 * wreg[5] + fd6 * wreg[6] + fd7 * wreg[7] +
                fd8 * wreg[8] + fd9 * wreg[9] + fd10 * wreg[10] + fd11 * wreg[11];
      dst[oyl * 64] = s;
#pragma unroll
      for (int k = 0; k < 10; ++k) wreg[k] = wreg[k + 2];
    }
  }
}

extern "C" void kernel_launch(void* const* d_in, const int* in_sizes, int n_in,
                              void* d_out, int out_size, void* d_ws, size_t ws_size,
                              hipStream_t stream) {
  const float* x = (const float*)d_in[0];
  const float* w = (const float*)d_in[1];
  const float* aw = (const float*)d_in[2];
  const float* ab = (const float*)d_in[3];
  const float* cw = (const float*)d_in[4];
  const float* cb = (const float*)d_in[5];
  const float* fu = (const float*)d_in[6];
  const float* fd = (const float*)d_in[7];
  char* ws = (char*)d_ws;
  float* styles = (float*)(ws + WS_STYLES);
  float* snorm = (float*)(ws + WS_SNORM);
  float* dmat = (float*)(ws + WS_D);
  float* W2 = (float*)(ws + WS_W2);
  __hip_bfloat16* At = (__hip_bfloat16*)(ws + WS_AT);
  __hip_bfloat16* xs = (__hip_bfloat16*)(ws + WS_XS);
  __hip_bfloat16* cvt = (__hip_bfloat16*)(ws + WS_CONV);
  float* out = (float*)d_out;

  k_styles<<<32, 256, 0, stream>>>(w, aw, ab, styles);
  k_snorm<<<1, 256, 0, stream>>>(styles, snorm);
  k_wprep<<<512, 256, 0, stream>>>(cw, At, W2);
  k_dcalc<<<32, 256, 0, stream>>>(W2, styles, snorm, dmat);
  k_zero_border<<<(16 * 528 * 64 + 255) / 256, 256, 0, stream>>>((uint4*)xs);
  k_scale_tr<<<dim3(8, 64, 16), 256, 0, stream>>>(x, styles, snorm, xs);
  k_gemm<<<1090, 256, 0, stream>>>(At, xs, dmat, cb, cvt);
  k_flrelu<<<dim3(512, 16), 512, 0, stream>>>(cvt, fu, fd, out);
}

// Round 6
// 781.653 us; speedup vs baseline: 1.2339x; 1.0601x over previous
//
#include <hip/hip_runtime.h>
#include <hip/hip_bf16.h>

typedef __attribute__((ext_vector_type(8))) short bf16x8;
typedef __attribute__((ext_vector_type(8))) unsigned short u16x8;
typedef __attribute__((ext_vector_type(4))) float f32x4;
typedef unsigned int u32;
typedef const __attribute__((address_space(1))) u32 glb_u32;
typedef __attribute__((address_space(3))) u32 lds_u32;

#define NB 16
#define CI 512
#define CO 512
#define PC 66              // conv output spatial (64 + 2*2 - 3 + 1)
#define PADD 68            // padded input spatial
#define NCOLS (NB*PC*PC)   // 69696

// workspace layout (bytes)
#define WS_STYLES 0ul              // 8192 f32
#define WS_D      33024ul          // 8192 f32
#define WS_W2     65792ul          // 512*512 f32
#define WS_AT     1114368ul        // 144*512*32 bf16 = 4718592
#define WS_XS     5832960ul        // 16*68*68*512 bf16 = 75759616
#define WS_CONV   81592576ul       // 16*512*66*66 bf16 = 71368704

// ---------------- fused prep: styles | weight-prep | xs border zero ----------------
// blocks 0..31: styles = w @ aw^T / sqrt(512) + bias
// blocks 32..543: per-o weight normalize -> tiled bf16 At + W2
// blocks 544..2655: zero the pad border of xs
__global__ __launch_bounds__(256) void k_prep(
    const float* __restrict__ w, const float* __restrict__ aw,
    const float* __restrict__ ab, const float* __restrict__ cw,
    float* __restrict__ styles, __hip_bfloat16* __restrict__ At,
    float* __restrict__ W2, uint4* __restrict__ xsv) {
  __shared__ float red[256];
  __shared__ float wnorm_s;
  const int bid = blockIdx.x;
  const int tid = threadIdx.x;

  if (bid < 32) {
    // ---- styles ----
    int idx = bid * 256 + tid;                 // 8192 = 16*512
    int n = idx >> 9, i = idx & 511;
    const float4* wr4 = (const float4*)(w + n * 512);
    const float4* ar4 = (const float4*)(aw + i * 512);
    float s = 0.f;
    for (int j = 0; j < 128; ++j) {
      float4 a = wr4[j], b = ar4[j];
      s += a.x * b.x + a.y * b.y + a.z * b.z + a.w * b.w;
    }
    styles[idx] = s * 0.04419417382415922f + ab[i];
  } else if (bid < 544) {
    // ---- wprep: kt = ic*9 + rs (ic = i>>5, rs = ry*3+rx); At[kt][o][ik] ----
    int o = bid - 32;
    const float* base = cw + o * 4608;
    float s = 0.f;
    for (int e = tid; e < 4608; e += 256) { float v = base[e]; s += v * v; }
    red[tid] = s;
    __syncthreads();
    for (int st = 128; st > 0; st >>= 1) {
      if (tid < st) red[tid] += red[tid + st];
      __syncthreads();
    }
    if (tid == 0) wnorm_s = rsqrtf(red[0] / 4608.f);
    __syncthreads();
    float wn = wnorm_s;
    for (int i = tid; i < 512; i += 256) {
      const float* e9 = cw + (o * 512 + i) * 9;
      float w2 = 0.f;
      int ic = i >> 5, ik = i & 31;
#pragma unroll
      for (int rs = 0; rs < 9; ++rs) {
        float wv = e9[rs] * wn;
        w2 += wv * wv;
        At[((ic * 9 + rs) * 512 + o) * 32 + ik] = __float2bfloat16(wv);
      }
      W2[o * 512 + i] = w2;
    }
  } else {
    // ---- zero xs border: 2112 blocks x 256 = 540672 = 16*528*64 exact ----
    int e = (bid - 544) * 256 + tid;
    int chunk = e & 63;
    int rest = e >> 6;
    int n = rest / 528;
    int pos = rest - n * 528;
    int row, col;
    if (pos < 272) {
      int r = pos / 68;
      row = (r < 2) ? r : r + 64;
      col = pos - r * 68;
    } else {
      int q = pos - 272;
      row = 2 + (q >> 2);
      int cs = q & 3;
      col = (cs < 2) ? cs : cs + 64;
    }
    uint4 z = {0u, 0u, 0u, 0u};
    xsv[(n * 4624 + row * 68 + col) * 64 + chunk] = z;
  }
}

// ---------------- scale_tr + embedded snorm + dcalc ----------------
// block (bx,by,bz): o = by*8+bx, n = bz -> computes dmat[n*512+o] locally;
// also computes snorm in-block (styles is L2-resident, 32 KB).
// Then: scale by styles[n,i]*snorm, transpose NCHW -> N,H+4,W+4,C (bf16).
__global__ __launch_bounds__(256) void k_scale_tr(
    const float* __restrict__ x, const float* __restrict__ styles,
    const float* __restrict__ W2, __hip_bfloat16* __restrict__ xs,
    float* __restrict__ dmat) {
  const int i0 = blockIdx.x * 64;
  const int p = blockIdx.y;
  const int n = blockIdx.z;
  const int o = blockIdx.y * 8 + blockIdx.x;
  const int tid = threadIdx.x;
  __shared__ float tile[64][65];
  __shared__ float2 red2[256];
  __shared__ float snorm_s;

  // dual reduction: global styles^2 sum (snorm) + per-(n,o) dcalc sum
  {
    float s2 = 0.f;
    const float4* st4 = (const float4*)styles;         // 2048 float4
    for (int j = tid; j < 2048; j += 256) {
      float4 v = st4[j];
      s2 += v.x * v.x + v.y * v.y + v.z * v.z + v.w * v.w;
    }
    float dsum = 0.f;
    if (tid < 128) {
      float4 a = ((const float4*)(W2 + o * 512))[tid];
      float4 b = ((const float4*)(styles + n * 512))[tid];
      dsum = a.x * b.x * b.x + a.y * b.y * b.y + a.z * b.z * b.z + a.w * b.w * b.w;
    }
    red2[tid] = make_float2(s2, dsum);
    __syncthreads();
    for (int st = 128; st > 0; st >>= 1) {
      if (tid < st) {
        red2[tid].x += red2[tid + st].x;
        red2[tid].y += red2[tid + st].y;
      }
      __syncthreads();
    }
    if (tid == 0) {
      float sn = rsqrtf(red2[0].x / 8192.f);
      dmat[n * 512 + o] = rsqrtf(sn * sn * red2[0].y + 1e-8f);
      snorm_s = sn;
    }
    __syncthreads();
  }
  const float sn = snorm_s;

  // stage 1: ch = tid>>4 (+16/rep), wq = (tid&15)*4; float4 load, scale, LDS
  {
    const int wq = (tid & 15) << 2;
#pragma unroll
    for (int rep = 0; rep < 4; ++rep) {
      int ch = (tid >> 4) + rep * 16;
      float sc = styles[n * 512 + i0 + ch] * sn;
      const float4 v = *(const float4*)(x + (((size_t)(n * 512 + i0 + ch) * 64 + p) * 64 + wq));
      tile[ch][wq + 0] = v.x * sc;
      tile[ch][wq + 1] = v.y * sc;
      tile[ch][wq + 2] = v.z * sc;
      tile[ch][wq + 3] = v.w * sc;
    }
  }
  __syncthreads();

  // stage 2: c8 = 8*(tid&7), q = (tid>>3) (+32/rep); pack 8 ch -> 16B store
  {
    const int c8 = (tid & 7) << 3;
    const size_t obase = ((size_t)n * 4624 + (size_t)(p + 2) * 68 + 2) * 512 + i0;
#pragma unroll
    for (int rep = 0; rep < 2; ++rep) {
      int q = (tid >> 3) + rep * 32;
      u16x8 pk;
#pragma unroll
      for (int j = 0; j < 8; ++j) {
        __hip_bfloat16 b = __float2bfloat16(tile[c8 + j][q]);
        pk[j] = *(unsigned short*)&b;
      }
      *(u16x8*)(xs + obase + (size_t)q * 512 + c8) = pk;
    }
  }
}

// ---------------- implicit GEMM conv: 256x128 tile, 256 threads, BK=32, 2 blocks/CU ----------------
__device__ __forceinline__ int colbase_of(int c) {
  c = c < (NCOLS - 1) ? c : (NCOLS - 1);
  int n = (int)((unsigned)c / 4356u);
  int rem = c - n * 4356;
  int p = (int)((unsigned)rem / 66u);
  int q = rem - p * 66;
  return (n * 4624 + p * 68 + q) * 512;
}

// LDS (static, 48 KiB): buf b at b*24576:
//   A: 256 rows x 32k bf16, packed 2 rows per 128B lds-row -> 128 lds-rows (16 KiB) @ +0
//   B: 128 cols x 32k bf16, same packing -> 64 lds-rows (8 KiB)  @ +16384
// 16B slot s within an lds-row p is XOR-swizzled: s_phys = s_log ^ (p&7) (involution).
// gload_lds dest is linear tid*16; swizzle realized by inverse-permuting the
// per-lane GLOBAL source (linear dest + inv-swz source + swz read).

#define GLD(G, L) __builtin_amdgcn_global_load_lds((glb_u32*)(G), (lds_u32*)(L), 16, 0, 0)
#define STAGE(KT2, KOFF2, CUR) do { \
    const char* _ga = AgA + (size_t)(KT2) * 32768; \
    char* _l = smem + (CUR) + sdst; \
    GLD(_ga, _l); \
    GLD(_ga + 4096, _l + 4096); \
    GLD(_ga + 8192, _l + 8192); \
    GLD(_ga + 12288, _l + 12288); \
    GLD(xsB0 + (KOFF2), _l + 16384); \
    GLD(xsB1 + (KOFF2), _l + 20480); } while (0)
#define BARR() __builtin_amdgcn_s_barrier()
#define LGKM() asm volatile("s_waitcnt lgkmcnt(0)" ::: "memory")
#define VMC6() asm volatile("s_waitcnt vmcnt(6)" ::: "memory")
#define VMC0() asm volatile("s_waitcnt vmcnt(0)" ::: "memory")

__global__ __launch_bounds__(256, 2) void k_gemm(
    const __hip_bfloat16* __restrict__ At, const __hip_bfloat16* __restrict__ xs,
    const float* __restrict__ dnorm, const float* __restrict__ cbias,
    __hip_bfloat16* __restrict__ cvt) {
  __shared__ __align__(16) char smem[49152];
  const int tid = threadIdx.x;

  // bijective XCD swizzle over nwg=1090 (q=136, r=2); (colt, ot) pairs adjacent so the
  // two o-tiles sharing a B panel land on the same XCD L2.
  const int bid = blockIdx.x;
  const int xcd = bid & 7, sidx = bid >> 3;
  const int wgid = (xcd < 2 ? xcd * 137 : 274 + (xcd - 2) * 136) + sidx;
  const int o0 = (wgid & 1) * 256;
  const int c0 = (wgid >> 1) * 128;

  const int lane = tid & 63, wave = tid >> 6;
  const int wr = wave >> 1, wc = wave & 1;          // 2M x 2N waves, 128x64 out each
  const int r16 = lane & 15, sx = lane >> 4;
  // fragment read offset inside a region: row R -> lds-row R>>1, slot ((R&1)*4+sx)^(R>>1 &7)
  const int poff = (r16 >> 1) * 128 + (((((r16 & 1) << 2) | sx)) ^ (r16 >> 1)) * 16;
  const int rdA = wr * 8192 + poff;                  // + m*1024 + curL
  const int rdB = 16384 + wc * 4096 + poff;          // + n*1024 + curL

  // staging constants: dest lds-row = h*32 + (tid>>3), phys slot = tid&7
  const int p8 = (tid >> 3) & 7;
  const int s_log = (tid & 7) ^ p8;
  const int r0 = 2 * (tid >> 3) + (s_log >> 2);      // source row within 64-row group
  const int kc = s_log & 3;                          // 16B chunk within 64B k-cell
  const int sdst = tid * 16;
  const char* AgA = (const char*)At + (size_t)(o0 + r0) * 64 + kc * 16;
  const char* xsC = (const char*)xs;
  const char* xsB0 = xsC + (size_t)(colbase_of(c0 + r0) * 2 + kc * 16);
  const char* xsB1 = xsC + (size_t)(colbase_of(c0 + 64 + r0) * 2 + kc * 16);

  f32x4 acc[8][4];
#pragma unroll
  for (int i = 0; i < 8; ++i)
#pragma unroll
    for (int j = 0; j < 4; ++j) acc[i][j] = (f32x4){0.f, 0.f, 0.f, 0.f};

  // prologue: stage tiles 0 and 1 (6 loads each); wait oldest 6 (tile 0)
  STAGE(0, 0, 0);
  STAGE(1, 1024, 24576);
  VMC6(); BARR();

  // kt -> B byte offset within a column: ry*69632 + rx*1024 + ic*64 (kt = ic*9 + ry*3 + rx)
  // OFF2[rs] = offset for rs2=(rs+2)%9 (compile-time under unroll)
  static const int OFF2[9] = {2048, 69632, 70656, 71680, 139264, 140288, 141312, 0, 1024};

  for (int ic = 0; ic < 16; ++ic) {
#pragma unroll
    for (int rs = 0; rs < 9; ++rs) {
      const int kt = ic * 9 + rs;
      const int curL = ((ic + rs) & 1) * 24576;
      bf16x8 af[8], bf[4];
#pragma unroll
      for (int m = 0; m < 8; ++m)
        af[m] = *(const bf16x8*)(smem + curL + rdA + m * 1024);
#pragma unroll
      for (int n = 0; n < 4; ++n)
        bf[n] = *(const bf16x8*)(smem + curL + rdB + n * 1024);
      LGKM();
      BARR();                                   // all waves done reading buf -> reusable
      if (kt < 142) {                           // stage tile kt+2 into the buffer just freed
        const int koff2 = OFF2[rs] + (ic + (rs + 2) / 9) * 64;
        STAGE(kt + 2, koff2, curL);
      }
      __builtin_amdgcn_s_setprio(1);
#pragma unroll
      for (int m = 0; m < 8; ++m)
#pragma unroll
        for (int n = 0; n < 4; ++n)
          acc[m][n] = __builtin_amdgcn_mfma_f32_16x16x32_bf16(af[m], bf[n], acc[m][n], 0, 0, 0);
      __builtin_amdgcn_s_setprio(0);
      if (kt < 143) {
        if (kt < 142) VMC6(); else VMC0();      // tile kt+1 landed (counted, no drain)
        BARR();
      }
    }
  }

  // epilogue: *d[n,o] + bias[o], store bf16 NCHW [16][512][66][66]
  const int cb2 = c0 + wc * 64 + r16;
  const int rb = o0 + wr * 128 + (sx << 2);
#pragma unroll
  for (int nt = 0; nt < 4; ++nt) {
    int c = cb2 + nt * 16;
    if (c < NCOLS) {
      int n = (int)((unsigned)c / 4356u);
      int cadr = c + n * 2225916;   // == n*512*4356 + p*66 + q
#pragma unroll
      for (int mt = 0; mt < 8; ++mt) {
#pragma unroll
        for (int reg = 0; reg < 4; ++reg) {
          int o = rb + mt * 16 + reg;
          float v = acc[mt][nt][reg] * dnorm[n * 512 + o] + cbias[o];
          cvt[cadr + o * 4356] = __float2bfloat16(v);
        }
      }
    }
  }
}

// ---------------- fused filtered_lrelu: full channel per block, sliding-window FIRs ----------------
#define CSW 76
#define VSW 77
#define DHW 67
__global__ __launch_bounds__(512) void k_flrelu(
    const __hip_bfloat16* __restrict__ cvt, const float* __restrict__ fup,
    const float* __restrict__ fdn, float* __restrict__ out) {
  const int ch = blockIdx.x;
  const int n = blockIdx.y;
  const int tid = threadIdx.x;

  __shared__ float u_s[9246];        // cs [75][76] then dh [138][67]
  __shared__ float vs_s[138 * VSW];  // vertical-up fine rows x coarse cols (stage A: raw bf16)

  const float fu0 = fup[0], fu1 = fup[1], fu2 = fup[2], fu3 = fup[3];
  const float fu4 = fup[4], fu5 = fup[5], fu6 = fup[6], fu7 = fup[7];
  const float fu8 = fup[8], fu9 = fup[9], fu10 = fup[10], fu11 = fup[11];
  const float fd0 = fdn[0], fd1 = fdn[1], fd2 = fdn[2], fd3 = fdn[3];
  const float fd4 = fdn[4], fd5 = fdn[5], fd6 = fdn[6], fd7 = fdn[7];
  const float fd8 = fdn[8], fd9 = fdn[9], fd10 = fdn[10], fd11 = fdn[11];

  const __hip_bfloat16* src = cvt + (size_t)(n * 512 + ch) * 4356;

  // stage A1: coalesced 8B raw copy of the 66x66 bf16 channel into vs_s scratch
  // (4356 bf16 = 8712 B = 1089 uint2; channel base is 8B-aligned since 8712%8==0)
  unsigned short* raw = (unsigned short*)vs_s;
  {
    const uint2* s2 = (const uint2*)src;
    uint2* d2 = (uint2*)raw;
    for (int e = tid; e < 1089; e += 512) d2[e] = s2[e];
  }
  __syncthreads();

  // stage A2: build coarse 75x75 f32 halo from LDS raw (zero outside [0,66)^2)
  for (int e = tid; e < 75 * 75; e += 512) {
    int il = (int)((unsigned)e / 75u);
    int jl = e - il * 75;
    int i = il - 4, j = jl - 4;
    float v = 0.f;
    if (i >= 0 && i < 66 && j >= 0 && j < 66)
      v = __bfloat162float(*(const __hip_bfloat16*)&raw[i * 66 + j]);
    u_s[il * CSW + jl] = v;
  }
  __syncthreads();   // raw fully consumed; stage B may overwrite vs_s

  // stage B: vertical up-FIR, fully parallel over (pair m, col jl)
  for (int e = tid; e < 69 * 75; e += 512) {
    int m = (int)((unsigned)e / 75u);   // 0..68
    int jl = e - m * 75;
    const float* col = u_s + jl;
    float c0 = col[(m + 0) * CSW], c1 = col[(m + 1) * CSW], c2 = col[(m + 2) * CSW];
    float c3 = col[(m + 3) * CSW], c4 = col[(m + 4) * CSW], c5 = col[(m + 5) * CSW];
    float ve = fu1 * c0 + fu3 * c1 + fu5 * c2 + fu7 * c3 + fu9 * c4 + fu11 * c5;
    float vo = fu0 * c0 + fu2 * c1 + fu4 * c2 + fu6 * c3 + fu8 * c4 + fu10 * c5;
    vs_s[(2 * m) * VSW + jl] = ve;
    vs_s[(2 * m + 1) * VSW + jl] = vo;
  }
  __syncthreads();

  // stage C: fused h-up + lrelu + h-down per fine row, transposed-FIR accumulators
  if (tid < 276) {
    int h = (tid >= 138) ? 1 : 0;
    int fy = tid - h * 138;
    const float* vrow = vs_s + fy * VSW + 32 * h;
    float* dhrow = u_s + fy * DHW + 32 * h;
    float a0 = 0.f, a1 = 0.f, a2 = 0.f, a3 = 0.f, a4 = 0.f, a5 = 0.f;
    float w0 = vrow[0], w1 = vrow[1], w2 = vrow[2], w3 = vrow[3], w4 = vrow[4];
#pragma unroll
    for (int ql = 0; ql < 37; ++ql) {
      float w5 = vrow[ql + 5];
      float ge = fu1 * w0 + fu3 * w1 + fu5 * w2 + fu7 * w3 + fu9 * w4 + fu11 * w5;
      float go = fu0 * w0 + fu2 * w1 + fu4 * w2 + fu6 * w3 + fu8 * w4 + fu10 * w5;
      ge *= (ge >= 0.f) ? 5.656854249492381f : 1.1313708498984762f;
      go *= (go >= 0.f) ? 5.656854249492381f : 1.1313708498984762f;
      ge = fminf(fmaxf(ge, -256.f), 256.f);
      go = fminf(fmaxf(go, -256.f), 256.f);
      a0 += fd10 * ge + fd11 * go;
      a1 += fd8 * ge + fd9 * go;
      a2 += fd6 * ge + fd7 * go;
      a3 += fd4 * ge + fd5 * go;
      a4 += fd2 * ge + fd3 * go;
      a5 += fd0 * ge + fd1 * go;
      if (ql >= 5) dhrow[ql - 5] = a0;
      a0 = a1; a1 = a2; a2 = a3; a3 = a4; a4 = a5; a5 = 0.f;
      w0 = w1; w1 = w2; w2 = w3; w3 = w4; w4 = w5;
    }
  }
  __syncthreads();

  // stage E: vertical down, 8 bands x 8 rows, 12-register sliding window
  {
    int ox = tid & 63;
    int r = tid >> 6;                // band: oy in [8r, 8r+8)
    const float* dcol = u_s + ox;
    int f0 = 16 * r;
    float wreg[12];
#pragma unroll
    for (int k = 0; k < 10; ++k) wreg[k] = dcol[(f0 + k) * DHW];
    float* dst = out + (((size_t)(n * 512 + ch) * 64 + 8 * r) * 64) + ox;
#pragma unroll
    for (int oyl = 0; oyl < 8; ++oyl) {
      wreg[10] = dcol[(f0 + 2 * oyl + 10) * DHW];
      wreg[11] = dcol[(f0 + 2 * oyl + 11) * DHW];
      float s = fd0 * wreg[0] + fd1 * wreg[1] + fd2 * wreg[2] + fd3 * wreg[3] +
                fd4 * wreg[4] + fd5 * wreg[5] + fd6 * wreg[6] + fd7 * wreg[7] +
                fd8 * wreg[8] + fd9 * wreg[9] + fd10 * wreg[10] + fd11 * wreg[11];
      dst[oyl * 64] = s;
#pragma unroll
      for (int k = 0; k < 10; ++k) wreg[k] = wreg[k + 2];
    }
  }
}

extern "C" void kernel_launch(void* const* d_in, const int* in_sizes, int n_in,
                              void* d_out, int out_size, void* d_ws, size_t ws_size,
                              hipStream_t stream) {
  const float* x = (const float*)d_in[0];
  const float* w = (const float*)d_in[1];
  const float* aw = (const float*)d_in[2];
  const float* ab = (const float*)d_in[3];
  const float* cw = (const float*)d_in[4];
  const float* cb = (const float*)d_in[5];
  const float* fu = (const float*)d_in[6];
  const float* fd = (const float*)d_in[7];
  char* ws = (char*)d_ws;
  float* styles = (float*)(ws + WS_STYLES);
  float* dmat = (float*)(ws + WS_D);
  float* W2 = (float*)(ws + WS_W2);
  __hip_bfloat16* At = (__hip_bfloat16*)(ws + WS_AT);
  __hip_bfloat16* xs = (__hip_bfloat16*)(ws + WS_XS);
  __hip_bfloat16* cvt = (__hip_bfloat16*)(ws + WS_CONV);
  float* out = (float*)d_out;

  k_prep<<<2656, 256, 0, stream>>>(w, aw, ab, cw, styles, At, W2, (uint4*)xs);
  k_scale_tr<<<dim3(8, 64, 16), 256, 0, stream>>>(x, styles, W2, xs, dmat);
  k_gemm<<<1090, 256, 0, stream>>>(At, xs, dmat, cb, cvt);
  k_flrelu<<<dim3(512, 16), 512, 0, stream>>>(cvt, fu, fd, out);
}